// Round 2
// baseline (2330.014 us; speedup 1.0000x reference)
//
#include <hip/hip_runtime.h>
#include <stdint.h>

// TemporalBlock: 4x (Linear(no bias) -> multi-step LIF[tau=2, vth=1, hard reset])
// x[4,32,1024,256] -> h1[.,512] -> gate -> gate -> out[.,256]
// Fused GEMM+LIF: each block computes a 64(bn) x 64(e) tile for ALL T=4 steps,
// scans LIF in registers, writes spikes (u8 for intermediates, f32 for output).

constexpr int T = 4;
constexpr int BNTOT = 32 * 1024; // B*N = 32768

// MODE 0: A=f32 x, out=u8 spikes          (input layer)
// MODE 1: A=u8 h,  out=u8 h*(1-s)         (hidden layers; h_old == A)
// MODE 2: A=u8 h,  out=f32 spikes         (output layer)
template <int MODE>
__global__ __launch_bounds__(256, 2)
void gemm_lif_kernel(const void* __restrict__ Av,
                     const float* __restrict__ W,
                     void* __restrict__ outv,
                     int K, int Nout)
{
    // As: [T][64 rows][20 floats] (BK=16 + pad to 20 keeps float4 align, 2-way max conflict)
    // Bs: K-major [16][68] so b-reads over cols are contiguous float4
    __shared__ __align__(16) float As[T * 64 * 20];
    __shared__ __align__(16) float Bs[16 * 68];

    const int tid = threadIdx.x;
    const int tx = tid & 15;   // col group
    const int ty = tid >> 4;   // row group
    const int row0 = blockIdx.x * 64;
    const int col0 = blockIdx.y * 64;

    float acc[T][4][4];
#pragma unroll
    for (int t = 0; t < T; ++t)
#pragma unroll
        for (int i = 0; i < 4; ++i)
#pragma unroll
            for (int j = 0; j < 4; ++j) acc[t][i][j] = 0.f;

    const int st = tid >> 6;  // A-stage: t  (one wave per t)
    const int sr = tid & 63;  // A-stage: row in tile
    const int br = tid >> 2;  // B-stage: col in tile
    const int bp = tid & 3;   // B-stage: k-part

    for (int k0 = 0; k0 < K; k0 += 16) {
        // ---- stage A tile: T*64 rows x 16 k ----
        {
            float* da = &As[(st * 64 + sr) * 20];
            const size_t aoff = ((size_t)st * BNTOT + row0 + sr) * (size_t)K + k0;
            if (MODE == 0) {
                const float* A = (const float*)Av;
                const float4* s4 = (const float4*)(A + aoff);
                float4 v0 = s4[0], v1 = s4[1], v2 = s4[2], v3 = s4[3];
                ((float4*)da)[0] = v0;
                ((float4*)da)[1] = v1;
                ((float4*)da)[2] = v2;
                ((float4*)da)[3] = v3;
            } else {
                const uint8_t* A = (const uint8_t*)Av;
                const uint4 b = *(const uint4*)(A + aoff);
                uint32_t wds[4] = {b.x, b.y, b.z, b.w};
#pragma unroll
                for (int q = 0; q < 16; ++q)
                    da[q] = (float)((wds[q >> 2] >> ((q & 3) * 8)) & 0xffu);
            }
        }
        // ---- stage B tile (transposed to k-major): 64 cols x 16 k ----
        {
            const float4 v = *(const float4*)(W + (size_t)(col0 + br) * K + k0 + bp * 4);
            Bs[(bp * 4 + 0) * 68 + br] = v.x;
            Bs[(bp * 4 + 1) * 68 + br] = v.y;
            Bs[(bp * 4 + 2) * 68 + br] = v.z;
            Bs[(bp * 4 + 3) * 68 + br] = v.w;
        }
        __syncthreads();

        // ---- compute: 4 k at a time ----
#pragma unroll
        for (int kk = 0; kk < 16; kk += 4) {
            float b[4][4]; // [q=k][j=col]
#pragma unroll
            for (int q = 0; q < 4; ++q) {
                const float4 bv = *(const float4*)&Bs[(kk + q) * 68 + tx * 4];
                b[q][0] = bv.x; b[q][1] = bv.y; b[q][2] = bv.z; b[q][3] = bv.w;
            }
#pragma unroll
            for (int t = 0; t < T; ++t) {
#pragma unroll
                for (int i = 0; i < 4; ++i) {
                    const float4 a = *(const float4*)&As[(t * 64 + ty * 4 + i) * 20 + kk];
#pragma unroll
                    for (int j = 0; j < 4; ++j) {
                        acc[t][i][j] = fmaf(a.x, b[0][j], acc[t][i][j]);
                        acc[t][i][j] = fmaf(a.y, b[1][j], acc[t][i][j]);
                        acc[t][i][j] = fmaf(a.z, b[2][j], acc[t][i][j]);
                        acc[t][i][j] = fmaf(a.w, b[3][j], acc[t][i][j]);
                    }
                }
            }
        }
        __syncthreads();
    }

    // ---- LIF epilogue: v <- (v+y)/2 ; s = (v>=1) ; v <- v*(1-s) ----
#pragma unroll
    for (int i = 0; i < 4; ++i) {
        const int row = row0 + ty * 4 + i;
        const int col = col0 + tx * 4;
        float v[4] = {0.f, 0.f, 0.f, 0.f};
#pragma unroll
        for (int t = 0; t < T; ++t) {
            const size_t off = ((size_t)t * BNTOT + row) * (size_t)Nout + col;
            bool sp[4];
#pragma unroll
            for (int j = 0; j < 4; ++j) {
                v[j] = 0.5f * (v[j] + acc[t][i][j]);
                sp[j] = (v[j] >= 1.0f);
                if (sp[j]) v[j] = 0.f;
            }
            if (MODE == 0) {
                uchar4 o;
                o.x = sp[0]; o.y = sp[1]; o.z = sp[2]; o.w = sp[3];
                *(uchar4*)((uint8_t*)outv + off) = o;
            } else if (MODE == 1) {
                const uint8_t* A = (const uint8_t*)Av;
                const uchar4 h = *(const uchar4*)(A + off);
                uchar4 o;
                o.x = sp[0] ? 0 : h.x;
                o.y = sp[1] ? 0 : h.y;
                o.z = sp[2] ? 0 : h.z;
                o.w = sp[3] ? 0 : h.w;
                *(uchar4*)((uint8_t*)outv + off) = o;
            } else {
                float4 o;
                o.x = sp[0] ? 1.f : 0.f;
                o.y = sp[1] ? 1.f : 0.f;
                o.z = sp[2] ? 1.f : 0.f;
                o.w = sp[3] ? 1.f : 0.f;
                *(float4*)((float*)outv + off) = o;
            }
        }
    }
}

extern "C" void kernel_launch(void* const* d_in, const int* in_sizes, int n_in,
                              void* d_out, int out_size, void* d_ws, size_t ws_size,
                              hipStream_t stream)
{
    const float* x     = (const float*)d_in[0];  // [4,32,1024,256]
    const float* w_in  = (const float*)d_in[1];  // [512,256]
    const float* w_h   = (const float*)d_in[2];  // [2,512,512]
    const float* w_out = (const float*)d_in[3];  // [256,512]
    float* out = (float*)d_out;                  // [4,32,1024,256]

    uint8_t* hA = (uint8_t*)d_ws;                      // 67.1 MB
    uint8_t* hB = hA + (size_t)T * BNTOT * 512;        // 67.1 MB  (total 128 MB)

    const dim3 blk(256);
    // input layer: x @ w_in^T -> LIF -> hA (u8 spikes)
    gemm_lif_kernel<0><<<dim3(BNTOT / 64, 512 / 64), blk, 0, stream>>>(x, w_in, hA, 256, 512);
    // hidden layer 0: h = hA * (1 - LIF(hA @ w_h0^T)) -> hB
    gemm_lif_kernel<1><<<dim3(BNTOT / 64, 512 / 64), blk, 0, stream>>>(hA, w_h, hB, 512, 512);
    // hidden layer 1: h = hB * (1 - LIF(hB @ w_h1^T)) -> hA
    gemm_lif_kernel<1><<<dim3(BNTOT / 64, 512 / 64), blk, 0, stream>>>(hB, w_h + 512 * 512, hA, 512, 512);
    // output layer: LIF(hA @ w_out^T) -> d_out (f32 spikes)
    gemm_lif_kernel<2><<<dim3(BNTOT / 64, 256 / 64), blk, 0, stream>>>(hA, w_out, out, 512, 256);
}

// Round 3
// 595.832 us; speedup vs baseline: 3.9105x; 3.9105x over previous
//
#include <hip/hip_runtime.h>
#include <stdint.h>

typedef __attribute__((ext_vector_type(8))) short short8;
typedef __attribute__((ext_vector_type(4))) float f32x4;

constexpr int T_ = 4;
constexpr int BNTOT = 32768; // B*N

__device__ __forceinline__ void gload_lds16(const void* g, void* lds) {
    __builtin_amdgcn_global_load_lds(
        (const __attribute__((address_space(1))) void*)g,
        (__attribute__((address_space(3))) void*)lds, 16, 0, 0);
}

// f32 -> bf16 (RNE) bit tricks; packs two into a u32
__device__ __forceinline__ uint32_t bf1(float f) {
    uint32_t x = __builtin_bit_cast(uint32_t, f);
    return (x + 0x7FFFu + ((x >> 16) & 1u)) >> 16;
}
__device__ __forceinline__ uint32_t pk(float lo, float hi) {
    return bf1(lo) | (bf1(hi) << 16);
}

// elementwise f32 -> bf16 (8 per thread)
__global__ __launch_bounds__(256)
void cvt_bf16(const float* __restrict__ in, ushort* __restrict__ out) {
    const size_t i = ((size_t)blockIdx.x * 256 + threadIdx.x) * 8;
    const float4 a = *(const float4*)(in + i);
    const float4 b = *(const float4*)(in + i + 4);
    uint4 o;
    o.x = pk(a.x, a.y); o.y = pk(a.z, a.w);
    o.z = pk(b.x, b.y); o.w = pk(b.z, b.w);
    *(uint4*)(out + i) = o;
}

// Fused bf16-MFMA GEMM (C = A @ W^T) + multi-step LIF over T=4.
// A: bf16 [T][BNTOT][K]; W: f32 [NOUT][K]; Out: [T][BNTOT][NOUT]
// MODE 0: out bf16 spikes; MODE 1: out bf16 h*(1-s) (gate h == A);
// MODE 2: out f32 spikes.
// Block: 256 thr = 4 waves; wave w computes 64x64 tile for t=w.
template <int MODE, int K, int NOUT>
__global__ __launch_bounds__(256, 2)
void lif_mfma(const ushort* __restrict__ A,
              const float* __restrict__ W,
              void* __restrict__ Out)
{
    // LDS: As[2][4][64][64]bf16 (0..65535), Bs[2][64][64]bf16 (65536..81919)
    // epilogue Y[4][64][64]f32 aliases As (0..65535)
    __shared__ __align__(16) char smem[81920];

    constexpr int NS = K / 64;

    const int tid = threadIdx.x;
    const int l   = tid & 63;
    const int w   = tid >> 6;          // wave = time step
    const int col0 = blockIdx.x * 64;  // col tiles fastest -> A panel L2-resident
    const int row0 = blockIdx.y * 64;

    // fragment-read lane constants
    const int rowbyte = (l & 15) << 7; // row-in-frag * 128B
    const int gx = l >> 4;             // k-granule sub-index 0..3
    const int sw = l & 7;              // swizzle key (== row&7 for frag reads)

    f32x4 acc[4][4];
#pragma unroll
    for (int m = 0; m < 4; ++m)
#pragma unroll
        for (int n = 0; n < 4; ++n) acc[m][n] = (f32x4)0.f;

    // ---- A staging (global_load_lds, pre-swizzled source granule) ----
    // chunk = 8 rows x 64k bf16 = 1KB; lane l -> (row=l>>3, granule l&7);
    // source granule = (l&7) ^ (l>>3) so LDS-linear == swizzled layout.
    const int a_rowin = l >> 3;
    const int a_gsrc  = (l & 7) ^ a_rowin;
    const ushort* a_base = A + (size_t)(w * BNTOT + row0 + a_rowin) * K + a_gsrc * 8;

    // ---- B staging (reg + cvt, swizzled ds_write) ----
    const int bc  = tid >> 2;  // col 0..63
    const int bkq = tid & 3;   // k-quarter (16 f32)
    const float* w_base = W + (size_t)(col0 + bc) * K + bkq * 16;
    const int b_g0 = (bkq * 2)     ^ (bc & 7);
    const int b_g1 = (bkq * 2 + 1) ^ (bc & 7);

    auto stageA = [&](int s, int buf) {
        const ushort* ap = a_base + (size_t)s * 64;
        char* ad = smem + buf * 32768 + w * 8192;
#pragma unroll
        for (int i = 0; i < 8; ++i)
            gload_lds16(ap + (size_t)i * 8 * K, ad + i * 1024);
    };
    auto writeB = [&](const float4& b0, const float4& b1,
                      const float4& b2, const float4& b3, int buf) {
        char* bd = smem + 65536 + buf * 8192 + bc * 128;
        uint4 lo, hi;
        lo.x = pk(b0.x, b0.y); lo.y = pk(b0.z, b0.w);
        lo.z = pk(b1.x, b1.y); lo.w = pk(b1.z, b1.w);
        hi.x = pk(b2.x, b2.y); hi.y = pk(b2.z, b2.w);
        hi.z = pk(b3.x, b3.y); hi.w = pk(b3.z, b3.w);
        *(uint4*)(bd + b_g0 * 16) = lo;
        *(uint4*)(bd + b_g1 * 16) = hi;
    };

    // ---- prologue: stage step 0 ----
    {
        const float* wp = w_base;
        float4 b0 = *(const float4*)(wp);
        float4 b1 = *(const float4*)(wp + 4);
        float4 b2 = *(const float4*)(wp + 8);
        float4 b3 = *(const float4*)(wp + 12);
        stageA(0, 0);
        writeB(b0, b1, b2, b3, 0);
    }
    __syncthreads();

    int buf = 0;
    for (int s = 0; s < NS; ++s) {
        const bool more = (s + 1 < NS);
        float4 b0, b1, b2, b3;
        if (more) { // issue next-tile loads early (latency hides under MFMA)
            const float* wp = w_base + (s + 1) * 64;
            b0 = *(const float4*)(wp);
            b1 = *(const float4*)(wp + 4);
            b2 = *(const float4*)(wp + 8);
            b3 = *(const float4*)(wp + 12);
            stageA(s + 1, buf ^ 1);
        }
        // compute on buf
        {
            const char* at = smem + buf * 32768 + w * 8192;
            const char* bt = smem + 65536 + buf * 8192;
#pragma unroll
            for (int kk = 0; kk < 2; ++kk) {
                const int go = (((kk * 4 + gx) ^ sw) << 4);
                short8 af[4], bfr[4];
#pragma unroll
                for (int m = 0; m < 4; ++m)
                    af[m] = *(const short8*)(at + m * 2048 + rowbyte + go);
#pragma unroll
                for (int n = 0; n < 4; ++n)
                    bfr[n] = *(const short8*)(bt + n * 2048 + rowbyte + go);
#pragma unroll
                for (int m = 0; m < 4; ++m)
#pragma unroll
                    for (int n = 0; n < 4; ++n)
                        acc[m][n] = __builtin_amdgcn_mfma_f32_16x16x32_bf16(
                            af[m], bfr[n], acc[m][n], 0, 0, 0);
            }
        }
        if (more) writeB(b0, b1, b2, b3, buf ^ 1); // write-late
        __syncthreads();
        buf ^= 1;
    }

    // ---- epilogue: Y tile to LDS (bank-spread), cross-t LIF scan ----
    {
        float* Yw = (float*)smem + w * 4096;
#pragma unroll
        for (int m = 0; m < 4; ++m)
#pragma unroll
            for (int n = 0; n < 4; ++n)
#pragma unroll
                for (int j = 0; j < 4; ++j) {
                    const int row = m * 16 + gx * 4 + j;
                    const int colp = (n * 16 + (l & 15)) ^ (((row >> 2) & 1) << 4);
                    Yw[row * 64 + colp] = acc[m][n][j];
                }
    }
    __syncthreads();
    {
        const int rr0 = tid >> 5;        // 0..7
        const int c2  = (tid & 31) * 2;  // even col
#pragma unroll
        for (int rb = 0; rb < 8; ++rb) {
            const int row = rb * 8 + rr0;
            const int cp  = c2 ^ (((row >> 2) & 1) << 4);
            float v0 = 0.f, v1 = 0.f;
#pragma unroll
            for (int t = 0; t < T_; ++t) {
                const float* Yt = (const float*)smem + t * 4096 + row * 64;
                const float y0 = Yt[cp], y1 = Yt[cp + 1];
                v0 = 0.5f * (v0 + y0);
                v1 = 0.5f * (v1 + y1);
                const bool s0 = (v0 >= 1.f), s1 = (v1 >= 1.f);
                v0 = s0 ? 0.f : v0;
                v1 = s1 ? 0.f : v1;
                const size_t orow = (size_t)(t * BNTOT + row0 + row);
                if (MODE == 0) {
                    uint32_t u = (s0 ? 0x3F80u : 0u) | (s1 ? 0x3F800000u : 0u);
                    *(uint32_t*)((ushort*)Out + orow * NOUT + col0 + c2) = u;
                } else if (MODE == 1) {
                    const uint32_t h = *(const uint32_t*)(A + orow * K + col0 + c2);
                    const uint32_t msk = (s0 ? 0u : 0xFFFFu) | (s1 ? 0u : 0xFFFF0000u);
                    *(uint32_t*)((ushort*)Out + orow * NOUT + col0 + c2) = h & msk;
                } else {
                    float2 o;
                    o.x = s0 ? 1.f : 0.f;
                    o.y = s1 ? 1.f : 0.f;
                    *(float2*)((float*)Out + orow * NOUT + col0 + c2) = o;
                }
            }
        }
    }
}

extern "C" void kernel_launch(void* const* d_in, const int* in_sizes, int n_in,
                              void* d_out, int out_size, void* d_ws, size_t ws_size,
                              hipStream_t stream)
{
    const float* x     = (const float*)d_in[0];  // [4,32,1024,256]
    const float* w_in  = (const float*)d_in[1];  // [512,256]
    const float* w_h   = (const float*)d_in[2];  // [2,512,512]
    const float* w_out = (const float*)d_in[3];  // [256,512]

    // buffer plan (d_out doubles as scratch; fully overwritten by L4):
    //   xbf = d_out[0:64MiB]     (bf16 x)
    //   hA  = d_ws[0:128MiB]     (bf16, L1 out / L2 in; reused as L3 out / L4 in)
    //   hB  = d_out[0:128MiB]    (bf16, L2 out / L3 in; xbf dead by then)
    ushort* xbf = (ushort*)d_out;
    ushort* hA  = (ushort*)d_ws;
    ushort* hB  = (ushort*)d_out;
    float*  out = (float*)d_out;

    cvt_bf16<<<16384, 256, 0, stream>>>(x, xbf); // 4*32768*256 / 2048

    lif_mfma<0, 256, 512><<<dim3(8, 512), 256, 0, stream>>>(xbf, w_in, hA);
    lif_mfma<1, 512, 512><<<dim3(8, 512), 256, 0, stream>>>(hA, w_h, hB);
    lif_mfma<1, 512, 512><<<dim3(8, 512), 256, 0, stream>>>(hB, w_h + 512 * 512, hA);
    lif_mfma<2, 512, 256><<<dim3(4, 512), 256, 0, stream>>>(hA, w_out, out);
}

// Round 4
// 421.219 us; speedup vs baseline: 5.5316x; 1.4145x over previous
//
#include <hip/hip_runtime.h>
#include <stdint.h>

typedef __attribute__((ext_vector_type(8))) short short8;
typedef __attribute__((ext_vector_type(4))) float f32x4;

constexpr int T_ = 4;
constexpr int BNTOT = 32768; // B*N

__device__ __forceinline__ void gload_lds16(const void* g, void* lds) {
    __builtin_amdgcn_global_load_lds(
        (const __attribute__((address_space(1))) void*)g,
        (__attribute__((address_space(3))) void*)lds, 16, 0, 0);
}

// f32 -> bf16 (RNE) bit tricks; packs two into a u32
__device__ __forceinline__ uint32_t bf1(float f) {
    uint32_t x = __builtin_bit_cast(uint32_t, f);
    return (x + 0x7FFFu + ((x >> 16) & 1u)) >> 16;
}
__device__ __forceinline__ uint32_t pk(float lo, float hi) {
    return bf1(lo) | (bf1(hi) << 16);
}

// elementwise f32 -> bf16 (8 per thread)
__global__ __launch_bounds__(256)
void cvt_bf16(const float* __restrict__ in, ushort* __restrict__ out) {
    const size_t i = ((size_t)blockIdx.x * 256 + threadIdx.x) * 8;
    const float4 a = *(const float4*)(in + i);
    const float4 b = *(const float4*)(in + i + 4);
    uint4 o;
    o.x = pk(a.x, a.y); o.y = pk(a.z, a.w);
    o.z = pk(b.x, b.y); o.w = pk(b.z, b.w);
    *(uint4*)(out + i) = o;
}

// Fused bf16-MFMA GEMM (C = A @ W^T) + multi-step LIF over T=4.
// A: bf16 [T][BNTOT][K]; W: f32 [NOUT][K]; Out: [T][BNTOT][NOUT]
// MODE 0: out bf16 spikes; MODE 1: out bf16 h*(1-s) (gate h == A);
// MODE 2: out f32 spikes.
// Block: 256 thr = 4 waves; wave w computes 64x64 tile for t=w.
// Grid: 1D, XCD-aware bijective swizzle so the NCOLT col-blocks sharing an
// A row-panel run consecutively on the SAME XCD (per-XCD L2 reuse).
template <int MODE, int K, int NOUT>
__global__ __launch_bounds__(256, 2)
void lif_mfma(const ushort* __restrict__ A,
              const float* __restrict__ W,
              void* __restrict__ Out)
{
    // LDS: As[2][4][64][64]bf16 (0..65535), Bs[2][64][64]bf16 (65536..81919)
    // epilogue Y[4][64][64]f32 aliases As (0..65535)
    __shared__ __align__(16) char smem[81920];

    constexpr int NS = K / 64;
    constexpr int NCOLT = NOUT / 64;

    const int tid = threadIdx.x;
    const int l   = tid & 63;
    const int w   = tid >> 6;          // wave = time step

    // XCD-aware swizzle: hardware round-robins linear block id across 8 XCDs.
    // xcd = id&7 owns row-tiles [xcd*64, xcd*64+64); col tiles sweep fastest.
    const int id  = blockIdx.x;
    const int xcd = id & 7;
    const int j_  = id >> 3;
    const int row0 = (xcd * 64 + j_ / NCOLT) * 64;
    const int col0 = (j_ % NCOLT) * 64;

    // fragment-read lane constants
    const int rowbyte = (l & 15) << 7; // row-in-frag * 128B
    const int gx = l >> 4;             // k-granule sub-index 0..3
    const int sw = l & 7;              // swizzle key (== row&7 for frag reads)

    f32x4 acc[4][4];
#pragma unroll
    for (int m = 0; m < 4; ++m)
#pragma unroll
        for (int n = 0; n < 4; ++n) acc[m][n] = (f32x4)0.f;

    // ---- A staging (global_load_lds, pre-swizzled source granule) ----
    // chunk = 8 rows x 64k bf16 = 1KB; lane l -> (row=l>>3, granule l&7);
    // source granule = (l&7) ^ (l>>3) so LDS-linear == swizzled layout.
    const int a_rowin = l >> 3;
    const int a_gsrc  = (l & 7) ^ a_rowin;
    const ushort* a_base = A + (size_t)(w * BNTOT + row0 + a_rowin) * K + a_gsrc * 8;

    // ---- B staging (reg + cvt, swizzled ds_write) ----
    const int bc  = tid >> 2;  // col 0..63
    const int bkq = tid & 3;   // k-quarter (16 f32)
    const float* w_base = W + (size_t)(col0 + bc) * K + bkq * 16;
    const int b_g0 = (bkq * 2)     ^ (bc & 7);
    const int b_g1 = (bkq * 2 + 1) ^ (bc & 7);

    auto stageA = [&](int s, int buf) {
        const ushort* ap = a_base + (size_t)s * 64;
        char* ad = smem + buf * 32768 + w * 8192;
#pragma unroll
        for (int i = 0; i < 8; ++i)
            gload_lds16(ap + (size_t)i * 8 * K, ad + i * 1024);
    };
    auto writeB = [&](const float4& b0, const float4& b1,
                      const float4& b2, const float4& b3, int buf) {
        char* bd = smem + 65536 + buf * 8192 + bc * 128;
        uint4 lo, hi;
        lo.x = pk(b0.x, b0.y); lo.y = pk(b0.z, b0.w);
        lo.z = pk(b1.x, b1.y); lo.w = pk(b1.z, b1.w);
        hi.x = pk(b2.x, b2.y); hi.y = pk(b2.z, b2.w);
        hi.z = pk(b3.x, b3.y); hi.w = pk(b3.z, b3.w);
        *(uint4*)(bd + b_g0 * 16) = lo;
        *(uint4*)(bd + b_g1 * 16) = hi;
    };

    // ---- prologue: stage step 0 ----
    {
        const float* wp = w_base;
        float4 b0 = *(const float4*)(wp);
        float4 b1 = *(const float4*)(wp + 4);
        float4 b2 = *(const float4*)(wp + 8);
        float4 b3 = *(const float4*)(wp + 12);
        stageA(0, 0);
        writeB(b0, b1, b2, b3, 0);
    }
    __syncthreads();

    int buf = 0;
    for (int s = 0; s < NS; ++s) {
        const bool more = (s + 1 < NS);
        float4 b0, b1, b2, b3;
        if (more) { // issue next-tile loads early (latency hides under MFMA)
            const float* wp = w_base + (s + 1) * 64;
            b0 = *(const float4*)(wp);
            b1 = *(const float4*)(wp + 4);
            b2 = *(const float4*)(wp + 8);
            b3 = *(const float4*)(wp + 12);
            stageA(s + 1, buf ^ 1);
        }
        // compute on buf
        {
            const char* at = smem + buf * 32768 + w * 8192;
            const char* bt = smem + 65536 + buf * 8192;
#pragma unroll
            for (int kk = 0; kk < 2; ++kk) {
                const int go = (((kk * 4 + gx) ^ sw) << 4);
                short8 af[4], bfr[4];
#pragma unroll
                for (int m = 0; m < 4; ++m)
                    af[m] = *(const short8*)(at + m * 2048 + rowbyte + go);
#pragma unroll
                for (int n = 0; n < 4; ++n)
                    bfr[n] = *(const short8*)(bt + n * 2048 + rowbyte + go);
#pragma unroll
                for (int m = 0; m < 4; ++m)
#pragma unroll
                    for (int n = 0; n < 4; ++n)
                        acc[m][n] = __builtin_amdgcn_mfma_f32_16x16x32_bf16(
                            af[m], bfr[n], acc[m][n], 0, 0, 0);
            }
        }
        if (more) writeB(b0, b1, b2, b3, buf ^ 1); // write-late
        __syncthreads();
        buf ^= 1;
    }

    // ---- epilogue: Y tile to LDS (bank-spread), cross-t LIF scan ----
    {
        float* Yw = (float*)smem + w * 4096;
#pragma unroll
        for (int m = 0; m < 4; ++m)
#pragma unroll
            for (int n = 0; n < 4; ++n)
#pragma unroll
                for (int j = 0; j < 4; ++j) {
                    const int row = m * 16 + gx * 4 + j;
                    const int colp = (n * 16 + (l & 15)) ^ (((row >> 2) & 1) << 4);
                    Yw[row * 64 + colp] = acc[m][n][j];
                }
    }
    __syncthreads();
    {
        const int rr0 = tid >> 5;        // 0..7
        const int c2  = (tid & 31) * 2;  // even col
#pragma unroll
        for (int rb = 0; rb < 8; ++rb) {
            const int row = rb * 8 + rr0;
            const int cp  = c2 ^ (((row >> 2) & 1) << 4);
            float v0 = 0.f, v1 = 0.f;
#pragma unroll
            for (int t = 0; t < T_; ++t) {
                const float* Yt = (const float*)smem + t * 4096 + row * 64;
                const float y0 = Yt[cp], y1 = Yt[cp + 1];
                v0 = 0.5f * (v0 + y0);
                v1 = 0.5f * (v1 + y1);
                const bool s0 = (v0 >= 1.f), s1 = (v1 >= 1.f);
                v0 = s0 ? 0.f : v0;
                v1 = s1 ? 0.f : v1;
                const size_t orow = (size_t)(t * BNTOT + row0 + row);
                if (MODE == 0) {
                    uint32_t u = (s0 ? 0x3F80u : 0u) | (s1 ? 0x3F800000u : 0u);
                    *(uint32_t*)((ushort*)Out + orow * NOUT + col0 + c2) = u;
                } else if (MODE == 1) {
                    const uint32_t h = *(const uint32_t*)(A + orow * K + col0 + c2);
                    const uint32_t msk = (s0 ? 0u : 0xFFFFu) | (s1 ? 0u : 0xFFFF0000u);
                    *(uint32_t*)((ushort*)Out + orow * NOUT + col0 + c2) = h & msk;
                } else {
                    float2 o;
                    o.x = s0 ? 1.f : 0.f;
                    o.y = s1 ? 1.f : 0.f;
                    *(float2*)((float*)Out + orow * NOUT + col0 + c2) = o;
                }
            }
        }
    }
}

extern "C" void kernel_launch(void* const* d_in, const int* in_sizes, int n_in,
                              void* d_out, int out_size, void* d_ws, size_t ws_size,
                              hipStream_t stream)
{
    const float* x     = (const float*)d_in[0];  // [4,32,1024,256]
    const float* w_in  = (const float*)d_in[1];  // [512,256]
    const float* w_h   = (const float*)d_in[2];  // [2,512,512]
    const float* w_out = (const float*)d_in[3];  // [256,512]

    // buffer plan (d_out doubles as scratch; fully overwritten by L4):
    //   xbf = d_out[0:64MiB]     (bf16 x)
    //   hA  = d_ws[0:128MiB]     (bf16, L1 out / L2 in; reused as L3 out / L4 in)
    //   hB  = d_out[0:128MiB]    (bf16, L2 out / L3 in; xbf dead by then)
    ushort* xbf = (ushort*)d_out;
    ushort* hA  = (ushort*)d_ws;
    ushort* hB  = (ushort*)d_out;
    float*  out = (float*)d_out;

    cvt_bf16<<<16384, 256, 0, stream>>>(x, xbf); // 4*32768*256 / 2048

    lif_mfma<0, 256, 512><<<8 * 512, 256, 0, stream>>>(xbf, w_in, hA);
    lif_mfma<1, 512, 512><<<8 * 512, 256, 0, stream>>>(hA, w_h, hB);
    lif_mfma<1, 512, 512><<<8 * 512, 256, 0, stream>>>(hB, w_h + 512 * 512, hA);
    lif_mfma<2, 512, 256><<<4 * 512, 256, 0, stream>>>(hA, w_out, out);
}